// Round 5
// baseline (273.176 us; speedup 1.0000x reference)
//
#include <hip/hip_runtime.h>
#include <hip/hip_bf16.h>
#include <stdint.h>

// SNN readout: h = inputs @ W^T (bf16 MFMA), then linear scan over T.
//   flt_t = ALPHA*flt_{t-1} + h_t ;  out_t = BETA*out_{t-1} + flt_{t-1}
// R5: (1) GEMM with NO LDS / NO barriers: 64x256 block tile, 4 waves on
// N-quarters issue identical A addresses (intra-CU sharing via L1/L2 -> A
// fetched once from HBM), B = pre-converted bf16 W loaded direct from L2.
// Fully unrolled K-loop, depth-1 A prefetch. (2) scan holds h in registers
// (H read once, not twice). Harness resets (~135us fills/restores) are fixed.

#define ALPHA 0.95f
#define BETA  0.9f

constexpr int Bdim = 64, T = 1000, Idim = 512, Odim = 256;
constexpr int M = Bdim * T;         // 64000 rows
constexpr int C = 40, L = 25;       // T = C*L

typedef short bf16x8 __attribute__((ext_vector_type(8)));
typedef float f32x4  __attribute__((ext_vector_type(4)));

__device__ inline uint32_t pk_bf16(float a, float b) {   // RNE pack
  union { float f; uint32_t u; } x, y; x.f = a; y.f = b;
  uint32_t lo = (x.u + 0x7FFFu + ((x.u >> 16) & 1u)) >> 16;
  uint32_t hi = (y.u + 0x7FFFu + ((y.u >> 16) & 1u)) & 0xFFFF0000u;
  return lo | hi;
}
__device__ inline uint16_t f2bf(float a) {
  union { float f; uint32_t u; } x; x.f = a;
  return (uint16_t)((x.u + 0x7FFFu + ((x.u >> 16) & 1u)) >> 16);
}
__device__ inline float bf2f(uint16_t h) {
  union { uint32_t u; float f; } x; x.u = ((uint32_t)h) << 16;
  return x.f;
}

// pack 8 fp32 (k-order) -> bf16x8 fragment via HW v_cvt_pk_bf16_f32
__device__ inline bf16x8 cvt8(float4 x0, float4 x1) {
  union { __hip_bfloat162 h[4]; bf16x8 v; } r;
  r.h[0] = __float22bfloat162_rn(make_float2(x0.x, x0.y));
  r.h[1] = __float22bfloat162_rn(make_float2(x0.z, x0.w));
  r.h[2] = __float22bfloat162_rn(make_float2(x1.x, x1.y));
  r.h[3] = __float22bfloat162_rn(make_float2(x1.z, x1.w));
  return r.v;
}

// -------- K0: W fp32 -> bf16 (RNE), 131072 elems --------
__global__ __launch_bounds__(256) void wconv(const float* __restrict__ W,
                                             uint16_t* __restrict__ Wbf) {
  int i = (blockIdx.x * 256 + threadIdx.x) * 8;
  float4 a = *(const float4*)(W + i);
  float4 b = *(const float4*)(W + i + 4);
  *(uint4*)(Wbf + i) = make_uint4(pk_bf16(a.x, a.y), pk_bf16(a.z, a.w),
                                  pk_bf16(b.x, b.y), pk_bf16(b.z, b.w));
}

// -------- K1: GEMM H[m][n] = sum_k A[m][k]*W[n][k], no LDS, no barriers ----
// grid 1000 (M/64), 256 thr. Wave w handles n in [w*64, w*64+64); all waves
// read the SAME A rows (L1/L2 dedupes). MFMA A/B operand: row = lane&15,
// k = (lane>>4)*8 + j, so each lane loads 32B of A (fp32) / 16B of B (bf16).
__global__ __launch_bounds__(256, 3) void gemm_h(const float* __restrict__ A,
                                                 const uint16_t* __restrict__ Wbf,
                                                 uint16_t* __restrict__ H) {
  const int tid  = threadIdx.x;
  const int lane = tid & 63;
  const int w    = tid >> 6;
  const int l15  = lane & 15;
  const int quad = lane >> 4;
  const int rm   = blockIdx.x * 64;

  const float*    ap[4];
  const uint16_t* bp[4];
#pragma unroll
  for (int t = 0; t < 4; ++t) {
    ap[t] = A   + (size_t)(rm + t * 16 + l15) * Idim + quad * 8;
    bp[t] = Wbf + (size_t)(w * 64 + t * 16 + l15) * Idim + quad * 8;
  }

  f32x4 acc[4][4] = {};

  float4 ca[4][2];                       // current A k-slice (fp32)
#pragma unroll
  for (int t = 0; t < 4; ++t) {
    ca[t][0] = *(const float4*)(ap[t]);
    ca[t][1] = *(const float4*)(ap[t] + 4);
  }

#pragma unroll
  for (int ks = 0; ks < 16; ++ks) {
    // B for this k-slice, straight from L2-resident Wbf
    bf16x8 bfr[4];
#pragma unroll
    for (int t = 0; t < 4; ++t) {
      union { uint4 u; bf16x8 v; } bb;
      bb.u = *(const uint4*)(bp[t] + ks * 32);
      bfr[t] = bb.v;
    }
    // prefetch next A slice (HBM latency hides under MFMA + other waves)
    float4 na[4][2];
    if (ks < 15) {
      const int ko = (ks + 1) * 32;
#pragma unroll
      for (int t = 0; t < 4; ++t) {
        na[t][0] = *(const float4*)(ap[t] + ko);
        na[t][1] = *(const float4*)(ap[t] + ko + 4);
      }
    }
    bf16x8 af[4];
#pragma unroll
    for (int t = 0; t < 4; ++t) af[t] = cvt8(ca[t][0], ca[t][1]);
#pragma unroll
    for (int mt = 0; mt < 4; ++mt)
#pragma unroll
      for (int nt = 0; nt < 4; ++nt)
        acc[mt][nt] = __builtin_amdgcn_mfma_f32_16x16x32_bf16(af[mt], bfr[nt], acc[mt][nt], 0, 0, 0);
    if (ks < 15) {
#pragma unroll
      for (int t = 0; t < 4; ++t) { ca[t][0] = na[t][0]; ca[t][1] = na[t][1]; }
    }
  }

  // epilogue: C/D layout col = lane&15, row = quad*4 + reg
#pragma unroll
  for (int mt = 0; mt < 4; ++mt)
#pragma unroll
    for (int nt = 0; nt < 4; ++nt)
#pragma unroll
      for (int r = 0; r < 4; ++r) {
        int gm = rm + mt * 16 + quad * 4 + r;
        int gn = w * 64 + nt * 16 + l15;
        H[(size_t)gm * Odim + gn] = f2bf(acc[mt][nt][r]);
      }
}

// -------- K2: whole scan in one kernel, h kept in registers --------
// grid 256 = (b, og): block owns 64 o's, all T. 640 thr: c = tid>>4 (40),
// ol = tid&15 (4 o's). Phase1 local scan (h -> regs) -> St(LDS); phase2
// in-LDS combine; phase3 rescan from registers, write Out.
constexpr double dpow(double x, int n) { double r = 1.0; for (int i = 0; i < n; ++i) r *= x; return r; }

__global__ __launch_bounds__(640) void scan_all(const uint16_t* __restrict__ H,
                                                float* __restrict__ Out) {
  constexpr float AL = (float)dpow(0.95, L);
  constexpr float BL = (float)dpow(0.90, L);
  constexpr float WL = (float)((dpow(0.95, L) - dpow(0.90, L)) / (0.95 - 0.90));
  __shared__ float2 St[C][64];

  const int b   = blockIdx.x >> 2;
  const int og  = blockIdx.x & 3;
  const int tid = threadIdx.x;
  const int c   = tid >> 4;
  const int ol  = tid & 15;

  const size_t base = ((size_t)b * T + c * L) * Odim + og * 64 + ol * 4;
  const ushort4* hp = (const ushort4*)(H + base);

  ushort4 hv[L];                        // 25 x 8B = 50 VGPRs, read H once
  // phase 1: local scan, zero init
  {
    float f[4] = {}, u[4] = {};
#pragma unroll
    for (int j = 0; j < L; ++j) {
      hv[j] = hp[j * 64];
      float h0 = bf2f(hv[j].x), h1 = bf2f(hv[j].y), h2 = bf2f(hv[j].z), h3 = bf2f(hv[j].w);
      float n0 = BETA * u[0] + f[0]; f[0] = ALPHA * f[0] + h0; u[0] = n0;
      float n1 = BETA * u[1] + f[1]; f[1] = ALPHA * f[1] + h1; u[1] = n1;
      float n2 = BETA * u[2] + f[2]; f[2] = ALPHA * f[2] + h2; u[2] = n2;
      float n3 = BETA * u[3] + f[3]; f[3] = ALPHA * f[3] + h3; u[3] = n3;
    }
#pragma unroll
    for (int i = 0; i < 4; ++i) St[c][ol * 4 + i] = make_float2(f[i], u[i]);
  }
  __syncthreads();

  // phase 2: combine across chunks in place (St[c] becomes that chunk's init)
  if (tid < 64) {
    float f = 0.f, u = 0.f;
#pragma unroll
    for (int cc = 0; cc < C; ++cc) {
      float2 s = St[cc][tid];
      St[cc][tid] = make_float2(f, u);
      float nu = BL * u + WL * f + s.y;   // uses old f
      f = AL * f + s.x;
      u = nu;
    }
  }
  __syncthreads();

  // phase 3: rescan from registers with chunk inits, write Out
  {
    float f[4], u[4];
#pragma unroll
    for (int i = 0; i < 4; ++i) { float2 s = St[c][ol * 4 + i]; f[i] = s.x; u[i] = s.y; }
    float4* op = (float4*)(Out + base);
#pragma unroll
    for (int j = 0; j < L; ++j) {
      float h0 = bf2f(hv[j].x), h1 = bf2f(hv[j].y), h2 = bf2f(hv[j].z), h3 = bf2f(hv[j].w);
      float4 o4;
      o4.x = BETA * u[0] + f[0]; f[0] = ALPHA * f[0] + h0; u[0] = o4.x;
      o4.y = BETA * u[1] + f[1]; f[1] = ALPHA * f[1] + h1; u[1] = o4.y;
      o4.z = BETA * u[2] + f[2]; f[2] = ALPHA * f[2] + h2; u[2] = o4.z;
      o4.w = BETA * u[3] + f[3]; f[3] = ALPHA * f[3] + h3; u[3] = o4.w;
      op[j * 64] = o4;
    }
  }
}

extern "C" void kernel_launch(void* const* d_in, const int* in_sizes, int n_in,
                              void* d_out, int out_size, void* d_ws, size_t ws_size,
                              hipStream_t stream) {
  const float* A = (const float*)d_in[0];   // (B, T, I) fp32
  const float* W = (const float*)d_in[1];   // (O, I) fp32
  float* Out = (float*)d_out;               // (B, T, O) fp32

  // workspace: H (bf16, 32.77MB) | Wbf (bf16, 0.25MB)
  uint16_t* H   = (uint16_t*)d_ws;
  uint16_t* Wbf = H + (size_t)M * Odim;

  wconv<<<Odim * Idim / (256 * 8), 256, 0, stream>>>(W, Wbf);
  gemm_h<<<M / 64, 256, 0, stream>>>(A, Wbf, H);
  scan_all<<<Bdim * 4, 640, 0, stream>>>(H, Out);
}

// Round 6
// 226.126 us; speedup vs baseline: 1.2081x; 1.2081x over previous
//
#include <hip/hip_runtime.h>
#include <hip/hip_bf16.h>
#include <stdint.h>

// SNN readout: h = inputs @ W^T (bf16 MFMA), then linear scan over T.
//   flt_t = ALPHA*flt_{t-1} + h_t ;  out_t = BETA*out_{t-1} + flt_{t-1}
// R6: GEMM back to the proven GLD16 2-barrier shape (R4, best 79us) but with
// 128x256 tile: staged traffic 384->262 MB, +50% compute per staged byte,
// same DMA queue depth (8 GLD16/thread/iter), 32KB LDS -> 2 blocks/CU.
// XOR-swizzled chunk placement encoded in GLOBAL addresses (GLD16 LDS dest
// is wave-uniform+lane*16, so LDS side must stay linear). Scan = R5 (passed).

#define ALPHA 0.95f
#define BETA  0.9f

constexpr int Bdim = 64, T = 1000, Idim = 512, Odim = 256;
constexpr int M = Bdim * T;         // 64000 rows
constexpr int C = 40, L = 25;       // T = C*L

typedef short bf16x8 __attribute__((ext_vector_type(8)));
typedef float f32x4  __attribute__((ext_vector_type(4)));

__device__ inline uint32_t pk_bf16(float a, float b) {   // RNE pack
  union { float f; uint32_t u; } x, y; x.f = a; y.f = b;
  uint32_t lo = (x.u + 0x7FFFu + ((x.u >> 16) & 1u)) >> 16;
  uint32_t hi = (y.u + 0x7FFFu + ((y.u >> 16) & 1u)) & 0xFFFF0000u;
  return lo | hi;
}
__device__ inline uint16_t f2bf(float a) {
  union { float f; uint32_t u; } x; x.f = a;
  return (uint16_t)((x.u + 0x7FFFu + ((x.u >> 16) & 1u)) >> 16);
}
__device__ inline float bf2f(uint16_t h) {
  union { uint32_t u; float f; } x; x.u = ((uint32_t)h) << 16;
  return x.f;
}

// async 16B global->LDS (wave-uniform LDS base + lane*16)
#define GLD16(g, l) __builtin_amdgcn_global_load_lds(                         \
    (const __attribute__((address_space(1))) uint32_t*)(g),                   \
    (__attribute__((address_space(3))) uint32_t*)(l), 16, 0, 0)

// pack 8 fp32 (k-order) -> bf16x8 fragment via HW v_cvt_pk_bf16_f32
__device__ inline bf16x8 cvt8(float4 x0, float4 x1) {
  union { __hip_bfloat162 h[4]; bf16x8 v; } r;
  r.h[0] = __float22bfloat162_rn(make_float2(x0.x, x0.y));
  r.h[1] = __float22bfloat162_rn(make_float2(x0.z, x0.w));
  r.h[2] = __float22bfloat162_rn(make_float2(x1.x, x1.y));
  r.h[3] = __float22bfloat162_rn(make_float2(x1.z, x1.w));
  return r.v;
}

// -------- K0: W fp32 -> bf16 (RNE), 131072 elems --------
__global__ __launch_bounds__(256) void wconv(const float* __restrict__ W,
                                             uint16_t* __restrict__ Wbf) {
  int i = (blockIdx.x * 256 + threadIdx.x) * 8;
  float4 a = *(const float4*)(W + i);
  float4 b = *(const float4*)(W + i + 4);
  *(uint4*)(Wbf + i) = make_uint4(pk_bf16(a.x, a.y), pk_bf16(a.z, a.w),
                                  pk_bf16(b.x, b.y), pk_bf16(b.z, b.w));
}

// -------- K1: GEMM H[m][n] = sum_k A[m][k]*W[n][k] --------
// grid 500 (M/128), 256 thr, 4 waves. Wave w: n-range [w*64, w*64+64), all 128 m.
// LDS: As fp32 128x32 (128B rows, 8 chunks of 16B; chunk g stored at slot g^(row&7));
//      Bs bf16 256x32 (64B rows, 4 chunks;            chunk g at slot g^(row&3)).
__global__ __launch_bounds__(256, 2) void gemm_h(const float* __restrict__ A,
                                                 const uint16_t* __restrict__ Wbf,
                                                 uint16_t* __restrict__ H) {
  __shared__ float    As[128 * 32];   // 16 KB
  __shared__ uint16_t Bs[256 * 32];   // 16 KB

  const int tid  = threadIdx.x;
  const int lane = tid & 63;
  const int w    = tid >> 6;
  const int l15  = lane & 15;
  const int quad = lane >> 4;
  const int rm   = blockIdx.x * 128;

  // ---- staging source addresses (swizzle folded into global address) ----
  // A: 4 calls/wave, call i: rows w*32 + i*8 + (lane>>3); slot lane&7 holds
  //    global chunk g = (lane&7) ^ (row&7); 16B = 4 fp32.
  const float* asrc[4];
  char*        aldst[4];
#pragma unroll
  for (int i = 0; i < 4; ++i) {
    int row = w * 32 + i * 8 + (lane >> 3);
    int g   = (lane & 7) ^ (row & 7);
    asrc[i]  = A + (size_t)(rm + row) * Idim + g * 4;
    aldst[i] = (char*)As + w * 4096 + i * 1024;
  }
  // B: 4 calls/wave, call i: rows w*64 + i*16 + (lane>>2); slot lane&3 holds
  //    chunk g = (lane&3) ^ (row&3); 16B = 8 bf16.
  const uint16_t* bsrc[4];
  char*           bldst[4];
#pragma unroll
  for (int i = 0; i < 4; ++i) {
    int row = w * 64 + i * 16 + (lane >> 2);
    int g   = (lane & 3) ^ (row & 3);
    bsrc[i]  = Wbf + (size_t)row * Idim + g * 8;
    bldst[i] = (char*)Bs + w * 4096 + i * 1024;
  }

  f32x4 acc[8][4] = {};

  for (int k0 = 0; k0 < Idim; k0 += 32) {
    __syncthreads();                       // prev iter's ds_reads done
#pragma unroll
    for (int i = 0; i < 4; ++i) GLD16(asrc[i] + k0, aldst[i]);
#pragma unroll
    for (int i = 0; i < 4; ++i) GLD16(bsrc[i] + k0, bldst[i]);
    __syncthreads();                       // vmcnt(0) drain + barrier

    // B fragments: n = w*64 + nt*16 + l15, chunk quad at slot quad^(n&3)
    bf16x8 bfr[4];
#pragma unroll
    for (int nt = 0; nt < 4; ++nt) {
      int n = w * 64 + nt * 16 + l15;
      bfr[nt] = *(const bf16x8*)&Bs[n * 32 + ((quad ^ (n & 3)) * 8)];
    }
    // A fragments: m = mt*16 + l15, chunks {2q,2q+1} at slots (2q)^(m&7), s^1
    bf16x8 af[8];
#pragma unroll
    for (int mt = 0; mt < 8; ++mt) {
      int m  = mt * 16 + l15;
      int s0 = (2 * quad) ^ (m & 7);
      float4 x0 = *(const float4*)&As[m * 32 + s0 * 4];
      float4 x1 = *(const float4*)&As[m * 32 + (s0 ^ 1) * 4];
      af[mt] = ((m & 1) == (m & 1)) ? cvt8(x0, x1) : cvt8(x0, x1);  // keep order
      // note: slot s0 holds chunk 2q, slot s0^1 holds chunk 2q+1 (since
      // (2q^x)^1 == (2q+1)^x for the low bit) -> x0 = k[8q..8q+3], x1 = k[8q+4..]
    }
#pragma unroll
    for (int mt = 0; mt < 8; ++mt)
#pragma unroll
      for (int nt = 0; nt < 4; ++nt)
        acc[mt][nt] = __builtin_amdgcn_mfma_f32_16x16x32_bf16(af[mt], bfr[nt], acc[mt][nt], 0, 0, 0);
  }

  // epilogue: C/D layout col = lane&15, row = quad*4 + reg
#pragma unroll
  for (int mt = 0; mt < 8; ++mt)
#pragma unroll
    for (int nt = 0; nt < 4; ++nt)
#pragma unroll
      for (int r = 0; r < 4; ++r) {
        int gm = rm + mt * 16 + quad * 4 + r;
        int gn = w * 64 + nt * 16 + l15;
        H[(size_t)gm * Odim + gn] = f2bf(acc[mt][nt][r]);
      }
}

// -------- K2: whole scan in one kernel, h kept in registers --------
// grid 256 = (b, og): block owns 64 o's, all T. 640 thr: c = tid>>4 (40),
// ol = tid&15 (4 o's). Phase1 local scan (h -> regs) -> St(LDS); phase2
// in-LDS combine; phase3 rescan from registers, write Out.
constexpr double dpow(double x, int n) { double r = 1.0; for (int i = 0; i < n; ++i) r *= x; return r; }

__global__ __launch_bounds__(640) void scan_all(const uint16_t* __restrict__ H,
                                                float* __restrict__ Out) {
  constexpr float AL = (float)dpow(0.95, L);
  constexpr float BL = (float)dpow(0.90, L);
  constexpr float WL = (float)((dpow(0.95, L) - dpow(0.90, L)) / (0.95 - 0.90));
  __shared__ float2 St[C][64];

  const int b   = blockIdx.x >> 2;
  const int og  = blockIdx.x & 3;
  const int tid = threadIdx.x;
  const int c   = tid >> 4;
  const int ol  = tid & 15;

  const size_t base = ((size_t)b * T + c * L) * Odim + og * 64 + ol * 4;
  const ushort4* hp = (const ushort4*)(H + base);

  ushort4 hv[L];                        // 25 x 8B = 50 VGPRs, read H once
  // phase 1: local scan, zero init
  {
    float f[4] = {}, u[4] = {};
#pragma unroll
    for (int j = 0; j < L; ++j) {
      hv[j] = hp[j * 64];
      float h0 = bf2f(hv[j].x), h1 = bf2f(hv[j].y), h2 = bf2f(hv[j].z), h3 = bf2f(hv[j].w);
      float n0 = BETA * u[0] + f[0]; f[0] = ALPHA * f[0] + h0; u[0] = n0;
      float n1 = BETA * u[1] + f[1]; f[1] = ALPHA * f[1] + h1; u[1] = n1;
      float n2 = BETA * u[2] + f[2]; f[2] = ALPHA * f[2] + h2; u[2] = n2;
      float n3 = BETA * u[3] + f[3]; f[3] = ALPHA * f[3] + h3; u[3] = n3;
    }
#pragma unroll
    for (int i = 0; i < 4; ++i) St[c][ol * 4 + i] = make_float2(f[i], u[i]);
  }
  __syncthreads();

  // phase 2: combine across chunks in place (St[c] becomes that chunk's init)
  if (tid < 64) {
    float f = 0.f, u = 0.f;
#pragma unroll
    for (int cc = 0; cc < C; ++cc) {
      float2 s = St[cc][tid];
      St[cc][tid] = make_float2(f, u);
      float nu = BL * u + WL * f + s.y;   // uses old f
      f = AL * f + s.x;
      u = nu;
    }
  }
  __syncthreads();

  // phase 3: rescan from registers with chunk inits, write Out
  {
    float f[4], u[4];
#pragma unroll
    for (int i = 0; i < 4; ++i) { float2 s = St[c][ol * 4 + i]; f[i] = s.x; u[i] = s.y; }
    float4* op = (float4*)(Out + base);
#pragma unroll
    for (int j = 0; j < L; ++j) {
      float h0 = bf2f(hv[j].x), h1 = bf2f(hv[j].y), h2 = bf2f(hv[j].z), h3 = bf2f(hv[j].w);
      float4 o4;
      o4.x = BETA * u[0] + f[0]; f[0] = ALPHA * f[0] + h0; u[0] = o4.x;
      o4.y = BETA * u[1] + f[1]; f[1] = ALPHA * f[1] + h1; u[1] = o4.y;
      o4.z = BETA * u[2] + f[2]; f[2] = ALPHA * f[2] + h2; u[2] = o4.z;
      o4.w = BETA * u[3] + f[3]; f[3] = ALPHA * f[3] + h3; u[3] = o4.w;
      op[j * 64] = o4;
    }
  }
}

extern "C" void kernel_launch(void* const* d_in, const int* in_sizes, int n_in,
                              void* d_out, int out_size, void* d_ws, size_t ws_size,
                              hipStream_t stream) {
  const float* A = (const float*)d_in[0];   // (B, T, I) fp32
  const float* W = (const float*)d_in[1];   // (O, I) fp32
  float* Out = (float*)d_out;               // (B, T, O) fp32

  // workspace: H (bf16, 32.77MB) | Wbf (bf16, 0.25MB)
  uint16_t* H   = (uint16_t*)d_ws;
  uint16_t* Wbf = H + (size_t)M * Odim;

  wconv<<<Odim * Idim / (256 * 8), 256, 0, stream>>>(W, Wbf);
  gemm_h<<<M / 128, 256, 0, stream>>>(A, Wbf, H);
  scan_all<<<Bdim * 4, 640, 0, stream>>>(H, Out);
}